// Round 2
// baseline (14546.922 us; speedup 1.0000x reference)
//
#include <hip/hip_runtime.h>
#include <cstdint>
#include <cstddef>

#define T_DIM 8
#define V_DIM 10000
#define E_DIM 100000

typedef __attribute__((ext_vector_type(8))) short short8;
typedef __attribute__((ext_vector_type(4))) float floatx4;

__device__ __forceinline__ unsigned int f2bf(float f) {
    union { float f; unsigned int u; } v; v.f = f;
    unsigned int u = v.u;
    u = u + 0x7FFFu + ((u >> 16) & 1u);   // RNE
    return u >> 16;
}
__device__ __forceinline__ float bf2f(unsigned short s) {
    union { unsigned int u; float f; } v; v.u = ((unsigned int)s) << 16;
    return v.f;
}

// ---- pack fp32 weight [K,Nw] into MFMA B-fragment order inside a concat buffer
// frag index f = kt*NTN_tot + nt_off + nt ; lane holds B[kt*32+(lane>>4)*8+j][nt*16+(lane&15)]
__global__ void pack_b_kernel(const float* __restrict__ w, unsigned short* __restrict__ out,
                              int K, int Nw, int NTN_tot, int nt_off) {
    int tid = blockIdx.x * blockDim.x + threadIdx.x;
    int total = (K >> 5) * (Nw >> 4) * 64;
    if (tid >= total) return;
    int lane = tid & 63;
    int f = tid >> 6;
    int ntn_w = Nw >> 4;
    int nt = f % ntn_w;
    int kt = f / ntn_w;
    int kbase = kt * 32 + ((lane >> 4) << 3);
    int n = nt * 16 + (lane & 15);
    unsigned int vals[8];
#pragma unroll
    for (int j = 0; j < 8; ++j)
        vals[j] = f2bf(w[(size_t)(kbase + j) * Nw + n]);
    uint4 pk;
    pk.x = vals[0] | (vals[1] << 16);
    pk.y = vals[2] | (vals[3] << 16);
    pk.z = vals[4] | (vals[5] << 16);
    pk.w = vals[6] | (vals[7] << 16);
    size_t fo = (size_t)kt * NTN_tot + nt_off + nt;
    *(uint4*)(out + (fo * 64 + lane) * 8) = pk;
}

// ---- token mixer: depthwise conv over t, k=3, pad 1; bf16 out ----
__global__ void token_mix_kernel(const float* __restrict__ xs, const float* __restrict__ w_pre,
                                 const float* __restrict__ b_pre, unsigned short* __restrict__ ob) {
    const int S = V_DIM * 128;   // per-t elements
    int tid = blockIdx.x * blockDim.x + threadIdx.x;
    if (tid >= T_DIM * S / 4) return;
    int e = tid * 4;
    int t = e / S;
    int c = e & 127;
    floatx4 xm = {0.f,0.f,0.f,0.f}, xp = {0.f,0.f,0.f,0.f};
    floatx4 x0 = *(const floatx4*)(xs + e);
    if (t > 0)          xm = *(const floatx4*)(xs + e - S);
    if (t < T_DIM - 1)  xp = *(const floatx4*)(xs + e + S);
    uint2 p; unsigned int b[4];
#pragma unroll
    for (int j = 0; j < 4; ++j) {
        int cc = c + j;
        float r = xm[j]*w_pre[cc*3+0] + x0[j]*w_pre[cc*3+1] + xp[j]*w_pre[cc*3+2] + b_pre[cc];
        b[j] = f2bf(r);
    }
    p.x = b[0] | (b[1] << 16);
    p.y = b[2] | (b[3] << 16);
    *(uint2*)(ob + e) = p;
}

// ---- lam0 = exp(-exp(a0)); C1[tau,kk] = B1[kk]*lam1^(7-tau) ----
__global__ void lamC_kernel(const float* __restrict__ a0, const float* __restrict__ a1,
                            const float* __restrict__ B1, float* __restrict__ lam0,
                            float* __restrict__ C1) {
    int i = blockIdx.x * blockDim.x + threadIdx.x;
    if (i >= 4096) return;
    lam0[i] = expf(-expf(a0[i]));
    float l1 = expf(-expf(a1[i]));
    float pw = B1[i];
    for (int tau = 7; tau >= 0; --tau) { C1[tau * 4096 + i] = pw; pw *= l1; }
}

// ---- bias concat: [b_res | b_sage | 0] per layer ----
__global__ void bias_cat_kernel(const float* __restrict__ br0, const float* __restrict__ bs0,
                                const float* __restrict__ br1, const float* __restrict__ bs1,
                                float* __restrict__ bcat0, float* __restrict__ bcat1) {
    int i = blockIdx.x * blockDim.x + threadIdx.x;
    if (i >= 768) return;
    bcat0[i] = (i < 256) ? br0[i] : (i < 512 ? bs0[i - 256] : 0.f);
    bcat1[i] = (i < 256) ? br1[i] : (i < 512 ? bs1[i - 256] : 0.f);
}

// ---- degree count + reciprocal ----
__global__ void deg_kernel(const int* __restrict__ ei, float* __restrict__ deg) {
    int tid = blockIdx.x * blockDim.x + threadIdx.x;
    if (tid >= T_DIM * E_DIM) return;
    int t = tid / E_DIM;
    int e = tid - t * E_DIM;
    int dst = ei[(size_t)t * 2 * E_DIM + E_DIM + e];
    if ((unsigned)dst < V_DIM) atomicAdd(deg + t * V_DIM + dst, 1.0f);
}
__global__ void invdeg_kernel(float* __restrict__ deg) {
    int tid = blockIdx.x * blockDim.x + threadIdx.x;
    if (tid >= T_DIM * V_DIM) return;
    deg[tid] = 1.0f / fmaxf(deg[tid], 1.0f);
}

// ---- scatter: h[dst] += xn[src] * invdeg[dst] (8 channels/thread) ----
__global__ void scatter_kernel(const unsigned short* __restrict__ xn, const int* __restrict__ ei,
                               const float* __restrict__ invdeg, float* __restrict__ h) {
    int tid = blockIdx.x * blockDim.x + threadIdx.x;
    if (tid >= E_DIM * 32) return;
    int e = tid >> 5;
    int c8 = (tid & 31) * 8;
    int src = ei[e];
    int dst = ei[E_DIM + e];
    if ((unsigned)src >= V_DIM || (unsigned)dst >= V_DIM) return;
    float s = invdeg[dst];
    short8 xv = *(const short8*)(xn + (size_t)src * 256 + c8);
    float* hp = h + (size_t)dst * 256 + c8;
#pragma unroll
    for (int j = 0; j < 8; ++j)
        atomicAdd(hp + j, bf2f((unsigned short)xv[j]) * s);
}

// ---- cast fp32 -> bf16 (x8 per thread) ----
__global__ void cast_bf16_kernel(const float* __restrict__ in, unsigned short* __restrict__ out, int n8) {
    int tid = blockIdx.x * blockDim.x + threadIdx.x;
    if (tid >= n8) return;
    int i = tid * 8;
    floatx4 a = *(const floatx4*)(in + i);
    floatx4 b = *(const floatx4*)(in + i + 4);
    uint4 pk;
    pk.x = f2bf(a[0]) | (f2bf(a[1]) << 16);
    pk.y = f2bf(a[2]) | (f2bf(a[3]) << 16);
    pk.z = f2bf(b[0]) | (f2bf(b[1]) << 16);
    pk.w = f2bf(b[2]) | (f2bf(b[3]) << 16);
    *(uint4*)(out + i) = pk;
}

// ---- layer-1 closed-form final state: state[v,kk] = sum_tau C1[tau,kk]*h[tau,v,kk>>4] ----
__global__ void state_eval_kernel(const unsigned short* __restrict__ hT, const float* __restrict__ C1,
                                  unsigned short* __restrict__ state) {
    int tid = blockIdx.x * blockDim.x + threadIdx.x;
    if (tid >= V_DIM * 512) return;
    int v = tid >> 9;
    int k0 = (tid & 511) * 8;
    int hh = k0 >> 4;
    float hv[8];
#pragma unroll
    for (int tau = 0; tau < 8; ++tau)
        hv[tau] = bf2f(hT[((size_t)tau * V_DIM + v) * 256 + hh]);
    float s[8];
#pragma unroll
    for (int j = 0; j < 8; ++j) s[j] = 0.f;
#pragma unroll
    for (int tau = 0; tau < 8; ++tau) {
        floatx4 c0 = *(const floatx4*)(C1 + tau * 4096 + k0);
        floatx4 c1 = *(const floatx4*)(C1 + tau * 4096 + k0 + 4);
#pragma unroll
        for (int j = 0; j < 4; ++j) { s[j] += hv[tau] * c0[j]; s[4 + j] += hv[tau] * c1[j]; }
    }
    uint4 pk;
    pk.x = f2bf(s[0]) | (f2bf(s[1]) << 16);
    pk.y = f2bf(s[2]) | (f2bf(s[3]) << 16);
    pk.z = f2bf(s[4]) | (f2bf(s[5]) << 16);
    pk.w = f2bf(s[6]) | (f2bf(s[7]) << 16);
    *(uint4*)(state + (size_t)v * 4096 + k0) = pk;
}

// ---- concat GEMM: x(t)[M,K] @ [w_res|w_self|w_neigh] -> xsr(f32+b), h(f32+b), xn(bf16)
// grid (12, cdiv(M,64)); wave = 16 rows x 64 cols; region uniform per block
__global__ __launch_bounds__(256)
void gemm_cat_kernel(const unsigned short* __restrict__ A, const unsigned short* __restrict__ Bp,
                     const float* __restrict__ bias, float* __restrict__ d0,
                     float* __restrict__ d1, unsigned short* __restrict__ d2,
                     int M, int K) {
    const int w = threadIdx.x >> 6, lane = threadIdx.x & 63;
    const int quad = lane >> 4, l16 = lane & 15;
    const int m0 = blockIdx.y * 64 + w * 16;
    const int ntb = blockIdx.x * 4;
    floatx4 acc[4];
#pragma unroll
    for (int i = 0; i < 4; ++i) acc[i] = (floatx4){0.f,0.f,0.f,0.f};
    int r = m0 + l16; if (r > M - 1) r = M - 1;
    const unsigned short* arow = A + (size_t)r * K + quad * 8;
    const int ksteps = K >> 5;
    for (int kt = 0; kt < ksteps; ++kt) {
        short8 af = *(const short8*)(arow + kt * 32);
#pragma unroll
        for (int i = 0; i < 4; ++i) {
            short8 bf = *(const short8*)(Bp + ((size_t)(kt * 48 + ntb + i) * 64 + lane) * 8);
            acc[i] = __builtin_amdgcn_mfma_f32_16x16x32_bf16(af, bf, acc[i], 0, 0, 0);
        }
    }
    const int region = blockIdx.x >> 2;
    const int rbase = m0 + quad * 4;
#pragma unroll
    for (int i = 0; i < 4; ++i) {
        int col = (ntb + i) * 16 + l16;
        int lcol = col & 255;
        float b = bias[col];
#pragma unroll
        for (int rr = 0; rr < 4; ++rr) {
            int row = rbase + rr;
            if (row < M) {
                float v = acc[i][rr] + b;
                size_t off = (size_t)row * 256 + lcol;
                if (region == 0) d0[off] = v;
                else if (region == 1) d1[off] = v;
                else d2[off] = (unsigned short)f2bf(v);
            }
        }
    }
}

// ---- layer-0 fused SSM + mix GEMM ----
// state RMW: s = first ? h*B : lam*s_old + h*B (bf16 writeback, single-writer per row)
// then y = relu(s) @ wmix + b_mix + xsr -> bf16 out. grid (157) 1-D, wave = 16 rows x 256 cols
__global__ __launch_bounds__(256)
void gemm_mix_ssm_kernel(unsigned short* __restrict__ state, const unsigned short* __restrict__ Bp,
                         const float* __restrict__ h, const float* __restrict__ lam,
                         const float* __restrict__ Bm, const float* __restrict__ bias,
                         const float* __restrict__ resid, unsigned short* __restrict__ outB,
                         int M, int first) {
    const int w = threadIdx.x >> 6, lane = threadIdx.x & 63;
    const int quad = lane >> 4, l16 = lane & 15;
    const int m0 = blockIdx.x * 64 + w * 16;
    int r = m0 + l16;
    const bool valid = (r < M);
    if (!valid) r = M - 1;
    unsigned short* srow = state + (size_t)r * 4096 + quad * 8;
    const float* hrow = h + (size_t)r * 256;
    floatx4 acc[16];
#pragma unroll
    for (int i = 0; i < 16; ++i) acc[i] = (floatx4){0.f,0.f,0.f,0.f};
    for (int kt = 0; kt < 128; ++kt) {
        const int kk = kt * 32 + quad * 8;
        float hv = hrow[kk >> 4];
        floatx4 lm0 = *(const floatx4*)(lam + kk);
        floatx4 lm1 = *(const floatx4*)(lam + kk + 4);
        floatx4 bm0 = *(const floatx4*)(Bm + kk);
        floatx4 bm1 = *(const floatx4*)(Bm + kk + 4);
        float sv[8];
        if (first) {
#pragma unroll
            for (int j = 0; j < 4; ++j) { sv[j] = hv * bm0[j]; sv[4+j] = hv * bm1[j]; }
        } else {
            short8 sold = *(const short8*)(srow + kt * 32);
#pragma unroll
            for (int j = 0; j < 4; ++j) {
                sv[j]   = lm0[j] * bf2f((unsigned short)sold[j])   + hv * bm0[j];
                sv[4+j] = lm1[j] * bf2f((unsigned short)sold[4+j]) + hv * bm1[j];
            }
        }
        unsigned int us[8];
#pragma unroll
        for (int j = 0; j < 8; ++j) us[j] = f2bf(sv[j]);
        if (valid) {
            uint4 pk;
            pk.x = us[0] | (us[1] << 16);
            pk.y = us[2] | (us[3] << 16);
            pk.z = us[4] | (us[5] << 16);
            pk.w = us[6] | (us[7] << 16);
            *(uint4*)(srow + kt * 32) = pk;
        }
        short8 af;
#pragma unroll
        for (int j = 0; j < 8; ++j)
            af[j] = (us[j] & 0x8000u) ? (short)0 : (short)us[j];   // bf16 relu
#pragma unroll
        for (int i = 0; i < 16; ++i) {
            short8 bf = *(const short8*)(Bp + ((size_t)(kt * 16 + i) * 64 + lane) * 8);
            acc[i] = __builtin_amdgcn_mfma_f32_16x16x32_bf16(af, bf, acc[i], 0, 0, 0);
        }
    }
    const int rbase = m0 + quad * 4;
#pragma unroll
    for (int i = 0; i < 16; ++i) {
        int col = i * 16 + l16;
        float b = bias[col];
#pragma unroll
        for (int rr = 0; rr < 4; ++rr) {
            int row = rbase + rr;
            if (row < M) {
                size_t off = (size_t)row * 256 + col;
                outB[off] = (unsigned short)f2bf(acc[i][rr] + b + resid[off]);
            }
        }
    }
}

// ---- plain GEMM (layer-1 mix, head). wave = 16 rows x NT*16 cols ----
template<int NT, bool RELU, bool RESID, bool BF16OUT>
__global__ __launch_bounds__(256)
void gemm_plain_kernel(const unsigned short* __restrict__ A, const unsigned short* __restrict__ Bp,
                       const float* __restrict__ bias, const float* __restrict__ resid,
                       float* __restrict__ outF, unsigned short* __restrict__ outB,
                       int M, int K, int NTN_tot) {
    const int w = threadIdx.x >> 6, lane = threadIdx.x & 63;
    const int quad = lane >> 4, l16 = lane & 15;
    const int m0 = blockIdx.y * 64 + w * 16;
    const int ntb = blockIdx.x * NT;
    const int Ntot = NTN_tot * 16;
    floatx4 acc[NT];
#pragma unroll
    for (int i = 0; i < NT; ++i) acc[i] = (floatx4){0.f,0.f,0.f,0.f};
    int r = m0 + l16; if (r > M - 1) r = M - 1;
    const unsigned short* arow = A + (size_t)r * K + quad * 8;
    const int ksteps = K >> 5;
    for (int kt = 0; kt < ksteps; ++kt) {
        short8 af = *(const short8*)(arow + kt * 32);
        if (RELU) {
#pragma unroll
            for (int j = 0; j < 8; ++j) {
                short s = af[j];
                af[j] = (s < 0) ? (short)0 : s;
            }
        }
#pragma unroll
        for (int i = 0; i < NT; ++i) {
            short8 bf = *(const short8*)(Bp + ((size_t)(kt * NTN_tot + ntb + i) * 64 + lane) * 8);
            acc[i] = __builtin_amdgcn_mfma_f32_16x16x32_bf16(af, bf, acc[i], 0, 0, 0);
        }
    }
    const int rbase = m0 + quad * 4;
#pragma unroll
    for (int i = 0; i < NT; ++i) {
        int col = (ntb + i) * 16 + l16;
        float b = bias[col];
#pragma unroll
        for (int rr = 0; rr < 4; ++rr) {
            int row = rbase + rr;
            if (row < M) {
                size_t off = (size_t)row * Ntot + col;
                float v = acc[i][rr] + b;
                if (RESID) v += resid[off];
                if (BF16OUT) outB[off] = (unsigned short)f2bf(v);
                else outF[off] = v;
            }
        }
    }
}

extern "C" void kernel_launch(void* const* d_in, const int* in_sizes, int n_in,
                              void* d_out, int out_size, void* d_ws, size_t ws_size,
                              hipStream_t stream) {
    const float* xs      = (const float*)d_in[0];
    const int*   ei      = (const int*)d_in[1];
    const float* w_pre   = (const float*)d_in[2];
    const float* b_pre   = (const float*)d_in[3];
    const float* w_res0  = (const float*)d_in[4];
    const float* b_res0  = (const float*)d_in[5];
    const float* w_self0 = (const float*)d_in[6];
    const float* w_neigh0= (const float*)d_in[7];
    const float* b_sage0 = (const float*)d_in[8];
    const float* a_log0  = (const float*)d_in[9];
    const float* B0      = (const float*)d_in[10];
    const float* w_mix0  = (const float*)d_in[11];
    const float* b_mix0  = (const float*)d_in[12];
    const float* w_res1  = (const float*)d_in[13];
    const float* b_res1  = (const float*)d_in[14];
    const float* w_self1 = (const float*)d_in[15];
    const float* w_neigh1= (const float*)d_in[16];
    const float* b_sage1 = (const float*)d_in[17];
    const float* a_log1  = (const float*)d_in[18];
    const float* B1      = (const float*)d_in[19];
    const float* w_mix1  = (const float*)d_in[20];
    const float* b_mix1  = (const float*)d_in[21];
    const float* w_out   = (const float*)d_in[22];
    const float* b_out   = (const float*)d_in[23];

    char* wsB = (char*)d_ws;
    size_t off = 0;
    auto alloc = [&](size_t bytes) {
        char* p = wsB + off;
        off += (bytes + 255) & ~(size_t)255;
        return p;
    };
    unsigned short* x0b   = (unsigned short*)alloc((size_t)T_DIM * V_DIM * 128 * 2);  // 20.5 MB
    unsigned short* x1b   = (unsigned short*)alloc((size_t)T_DIM * V_DIM * 256 * 2);  // 41 MB
    unsigned short* hT_b  = (unsigned short*)alloc((size_t)T_DIM * V_DIM * 256 * 2);  // 41 MB
    float*          h_t   = (float*)alloc((size_t)V_DIM * 256 * 4);                   // 10.2 MB
    unsigned short* xn_t  = (unsigned short*)alloc((size_t)V_DIM * 256 * 2);          // 5.1 MB
    float*          xsr_t = (float*)alloc((size_t)V_DIM * 256 * 4);                   // 10.2 MB
    unsigned short* state = (unsigned short*)alloc((size_t)V_DIM * 4096 * 2);         // 82 MB
    float*          deg   = (float*)alloc((size_t)T_DIM * V_DIM * 4);
    unsigned short* out1_b= (unsigned short*)alloc((size_t)V_DIM * 256 * 2);
    float*          lam0  = (float*)alloc(4096 * 4);
    float*          C1    = (float*)alloc(8 * 4096 * 4);
    float*          bcat0 = (float*)alloc(768 * 4);
    float*          bcat1 = (float*)alloc(768 * 4);
    unsigned short* wcat0p= (unsigned short*)alloc((size_t)128 * 768 * 2);
    unsigned short* wcat1p= (unsigned short*)alloc((size_t)256 * 768 * 2);
    unsigned short* wmix0p= (unsigned short*)alloc((size_t)4096 * 256 * 2);
    unsigned short* wmix1p= (unsigned short*)alloc((size_t)4096 * 256 * 2);
    unsigned short* woutp = (unsigned short*)alloc((size_t)256 * 64 * 2);
    if (off > ws_size) return;   // ws exhausted: fail cleanly (absmax), not a GPU fault

    auto cdiv = [](int a, int b) { return (a + b - 1) / b; };

    // ---- parameter prep ----
    lamC_kernel<<<16, 256, 0, stream>>>(a_log0, a_log1, B1, lam0, C1);
    bias_cat_kernel<<<3, 256, 0, stream>>>(b_res0, b_sage0, b_res1, b_sage1, bcat0, bcat1);
    pack_b_kernel<<<cdiv(4*16*64, 256), 256, 0, stream>>>(w_res0,   wcat0p, 128, 256, 48, 0);
    pack_b_kernel<<<cdiv(4*16*64, 256), 256, 0, stream>>>(w_self0,  wcat0p, 128, 256, 48, 16);
    pack_b_kernel<<<cdiv(4*16*64, 256), 256, 0, stream>>>(w_neigh0, wcat0p, 128, 256, 48, 32);
    pack_b_kernel<<<cdiv(8*16*64, 256), 256, 0, stream>>>(w_res1,   wcat1p, 256, 256, 48, 0);
    pack_b_kernel<<<cdiv(8*16*64, 256), 256, 0, stream>>>(w_self1,  wcat1p, 256, 256, 48, 16);
    pack_b_kernel<<<cdiv(8*16*64, 256), 256, 0, stream>>>(w_neigh1, wcat1p, 256, 256, 48, 32);
    pack_b_kernel<<<cdiv(128*16*64, 256), 256, 0, stream>>>(w_mix0, wmix0p, 4096, 256, 16, 0);
    pack_b_kernel<<<cdiv(128*16*64, 256), 256, 0, stream>>>(w_mix1, wmix1p, 4096, 256, 16, 0);
    pack_b_kernel<<<cdiv(8*4*64, 256), 256, 0, stream>>>(w_out, woutp, 256, 64, 4, 0);

    // ---- token mixer + degrees ----
    token_mix_kernel<<<cdiv(T_DIM*V_DIM*128/4, 256), 256, 0, stream>>>(xs, w_pre, b_pre, x0b);
    hipMemsetAsync(deg, 0, (size_t)T_DIM * V_DIM * 4, stream);
    deg_kernel<<<cdiv(T_DIM*E_DIM, 256), 256, 0, stream>>>(ei, deg);
    invdeg_kernel<<<cdiv(T_DIM*V_DIM, 256), 256, 0, stream>>>(deg);

    const int gM = cdiv(V_DIM, 64);   // 157

    // ================= LAYER 0 =================
    for (int t = 0; t < T_DIM; ++t) {
        gemm_cat_kernel<<<dim3(12, gM), 256, 0, stream>>>(
            x0b + (size_t)t * V_DIM * 128, wcat0p, bcat0, xsr_t, h_t, xn_t, V_DIM, 128);
        scatter_kernel<<<cdiv(E_DIM*32, 256), 256, 0, stream>>>(
            xn_t, ei + (size_t)t * 2 * E_DIM, deg + (size_t)t * V_DIM, h_t);
        gemm_mix_ssm_kernel<<<gM, 256, 0, stream>>>(
            state, wmix0p, h_t, lam0, B0, b_mix0, xsr_t,
            x1b + (size_t)t * V_DIM * 256, V_DIM, t == 0 ? 1 : 0);
    }

    // ================= LAYER 1 =================
    for (int t = 0; t < T_DIM; ++t) {
        gemm_cat_kernel<<<dim3(12, gM), 256, 0, stream>>>(
            x1b + (size_t)t * V_DIM * 256, wcat1p, bcat1, xsr_t, h_t, xn_t, V_DIM, 256);
        scatter_kernel<<<cdiv(E_DIM*32, 256), 256, 0, stream>>>(
            xn_t, ei + (size_t)t * 2 * E_DIM, deg + (size_t)t * V_DIM, h_t);
        cast_bf16_kernel<<<cdiv(V_DIM*32, 256), 256, 0, stream>>>(
            h_t, hT_b + (size_t)t * V_DIM * 256, V_DIM * 32);
    }
    // closed-form state(7), then mix GEMM with residual from t=7's xsr
    state_eval_kernel<<<cdiv(V_DIM*512, 256), 256, 0, stream>>>(hT_b, C1, state);
    gemm_plain_kernel<16, true, true, true><<<dim3(1, gM), 256, 0, stream>>>(
        state, wmix1p, b_mix1, xsr_t, nullptr, out1_b, V_DIM, 4096, 16);

    // ================= head =================
    gemm_plain_kernel<4, false, false, false><<<dim3(1, gM), 256, 0, stream>>>(
        out1_b, woutp, b_out, nullptr, (float*)d_out, nullptr, V_DIM, 256, 4);
}

// Round 3
// 2203.002 us; speedup vs baseline: 6.6032x; 6.6032x over previous
//
#include <hip/hip_runtime.h>
#include <cstdint>
#include <cstddef>

#define T_DIM 8
#define V_DIM 10000
#define E_DIM 100000

typedef __attribute__((ext_vector_type(8))) short short8;
typedef __attribute__((ext_vector_type(4))) float floatx4;

__device__ __forceinline__ unsigned int f2bf(float f) {
    union { float f; unsigned int u; } v; v.f = f;
    unsigned int u = v.u;
    u = u + 0x7FFFu + ((u >> 16) & 1u);   // RNE
    return u >> 16;
}
__device__ __forceinline__ float bf2f(unsigned int s) {
    union { unsigned int u; float f; } v; v.u = s << 16;
    return v.f;
}

// ---- pack fp32 weight [K,Nw] into MFMA B-fragment order inside a concat buffer
__global__ void pack_b_kernel(const float* __restrict__ w, unsigned short* __restrict__ out,
                              int K, int Nw, int NTN_tot, int nt_off) {
    int tid = blockIdx.x * blockDim.x + threadIdx.x;
    int total = (K >> 5) * (Nw >> 4) * 64;
    if (tid >= total) return;
    int lane = tid & 63;
    int f = tid >> 6;
    int ntn_w = Nw >> 4;
    int nt = f % ntn_w;
    int kt = f / ntn_w;
    int kbase = kt * 32 + ((lane >> 4) << 3);
    int n = nt * 16 + (lane & 15);
    unsigned int vals[8];
#pragma unroll
    for (int j = 0; j < 8; ++j)
        vals[j] = f2bf(w[(size_t)(kbase + j) * Nw + n]);
    uint4 pk;
    pk.x = vals[0] | (vals[1] << 16);
    pk.y = vals[2] | (vals[3] << 16);
    pk.z = vals[4] | (vals[5] << 16);
    pk.w = vals[6] | (vals[7] << 16);
    size_t fo = (size_t)kt * NTN_tot + nt_off + nt;
    *(uint4*)(out + (fo * 64 + lane) * 8) = pk;
}

// ---- token mixer ----
__global__ void token_mix_kernel(const float* __restrict__ xs, const float* __restrict__ w_pre,
                                 const float* __restrict__ b_pre, unsigned short* __restrict__ ob) {
    const int S = V_DIM * 128;
    int tid = blockIdx.x * blockDim.x + threadIdx.x;
    if (tid >= T_DIM * S / 4) return;
    int e = tid * 4;
    int t = e / S;
    int c = e & 127;
    floatx4 xm = {0.f,0.f,0.f,0.f}, xp = {0.f,0.f,0.f,0.f};
    floatx4 x0 = *(const floatx4*)(xs + e);
    if (t > 0)          xm = *(const floatx4*)(xs + e - S);
    if (t < T_DIM - 1)  xp = *(const floatx4*)(xs + e + S);
    uint2 p; unsigned int b[4];
#pragma unroll
    for (int j = 0; j < 4; ++j) {
        int cc = c + j;
        float r = xm[j]*w_pre[cc*3+0] + x0[j]*w_pre[cc*3+1] + xp[j]*w_pre[cc*3+2] + b_pre[cc];
        b[j] = f2bf(r);
    }
    p.x = b[0] | (b[1] << 16);
    p.y = b[2] | (b[3] << 16);
    *(uint2*)(ob + e) = p;
}

// ---- lam0 = exp(-exp(a0)); C1[tau,kk] = B1[kk]*lam1^(7-tau) ----
__global__ void lamC_kernel(const float* __restrict__ a0, const float* __restrict__ a1,
                            const float* __restrict__ B1, float* __restrict__ lam0,
                            float* __restrict__ C1) {
    int i = blockIdx.x * blockDim.x + threadIdx.x;
    if (i >= 4096) return;
    lam0[i] = expf(-expf(a0[i]));
    float l1 = expf(-expf(a1[i]));
    float pw = B1[i];
    for (int tau = 7; tau >= 0; --tau) { C1[tau * 4096 + i] = pw; pw *= l1; }
}

__global__ void bias_cat_kernel(const float* __restrict__ br0, const float* __restrict__ bs0,
                                const float* __restrict__ br1, const float* __restrict__ bs1,
                                float* __restrict__ bcat0, float* __restrict__ bcat1) {
    int i = blockIdx.x * blockDim.x + threadIdx.x;
    if (i >= 768) return;
    bcat0[i] = (i < 256) ? br0[i] : (i < 512 ? bs0[i - 256] : 0.f);
    bcat1[i] = (i < 256) ? br1[i] : (i < 512 ? bs1[i - 256] : 0.f);
}

// ================= CSR build =================
__global__ void deg_kernel(const int* __restrict__ ei, int* __restrict__ deg_cnt) {
    int tid = blockIdx.x * blockDim.x + threadIdx.x;
    if (tid >= T_DIM * E_DIM) return;
    int t = tid / E_DIM;
    int e = tid - t * E_DIM;
    int dst = ei[(size_t)t * 2 * E_DIM + E_DIM + e];
    if ((unsigned)dst < V_DIM) atomicAdd(deg_cnt + t * V_DIM + dst, 1);
}

__global__ void invdeg_kernel(const int* __restrict__ deg_cnt, float* __restrict__ inv) {
    int tid = blockIdx.x * blockDim.x + threadIdx.x;
    if (tid >= T_DIM * V_DIM) return;
    inv[tid] = 1.0f / (float)max(deg_cnt[tid], 1);
}

// one block per t; exclusive prefix sum of deg into rowptr[t*(V+1)..]
__global__ __launch_bounds__(1024)
void scan_kernel(const int* __restrict__ deg_cnt, int* __restrict__ rowptr) {
    __shared__ int sums[1024];
    int t = blockIdx.x;
    const int* d = deg_cnt + t * V_DIM;
    int* rp = rowptr + t * (V_DIM + 1);
    int tid = threadIdx.x;
    int base = tid * 10;
    int loc[10]; int s = 0;
#pragma unroll
    for (int j = 0; j < 10; ++j) {
        int v = base + j;
        int x = (v < V_DIM) ? d[v] : 0;
        loc[j] = s; s += x;
    }
    sums[tid] = s;
    __syncthreads();
    for (int o = 1; o < 1024; o <<= 1) {
        int v = (tid >= o) ? sums[tid - o] : 0;
        __syncthreads();
        sums[tid] += v;
        __syncthreads();
    }
    int prev = (tid == 0) ? 0 : sums[tid - 1];
#pragma unroll
    for (int j = 0; j < 10; ++j) {
        int v = base + j;
        if (v < V_DIM) rp[v] = prev + loc[j];
    }
    if (tid == 1023) rp[V_DIM] = sums[1023];
}

__global__ void fill_kernel(const int* __restrict__ ei, const int* __restrict__ rowptr,
                            int* __restrict__ fill_cnt, int* __restrict__ srcs) {
    int tid = blockIdx.x * blockDim.x + threadIdx.x;
    if (tid >= T_DIM * E_DIM) return;
    int t = tid / E_DIM;
    int e = tid - t * E_DIM;
    const int* eit = ei + (size_t)t * 2 * E_DIM;
    int src = eit[e];
    int dst = eit[E_DIM + e];
    if ((unsigned)src >= V_DIM || (unsigned)dst >= V_DIM) return;
    int pos = rowptr[t * (V_DIM + 1) + dst] + atomicAdd(fill_cnt + t * V_DIM + dst, 1);
    srcs[(size_t)t * E_DIM + pos] = src;
}

// ---- gather: hb[v] += (sum_{src in bucket(v)} xn[src]) * invdeg[v]; one wave per v
__global__ void gather_kernel(const unsigned short* __restrict__ xn, const int* __restrict__ srcs,
                              const int* __restrict__ rowptr, const float* __restrict__ invdeg,
                              unsigned short* __restrict__ hb) {
    int gw = (blockIdx.x * blockDim.x + threadIdx.x) >> 6;
    int lane = threadIdx.x & 63;
    if (gw >= V_DIM) return;
    int beg = rowptr[gw], end = rowptr[gw + 1];
    float a0 = 0.f, a1 = 0.f, a2 = 0.f, a3 = 0.f;
    for (int i = beg; i < end; ++i) {
        int s = srcs[i];
        uint2 p = *(const uint2*)(xn + (size_t)s * 256 + lane * 4);
        a0 += bf2f(p.x & 0xffffu);
        a1 += bf2f(p.x >> 16);
        a2 += bf2f(p.y & 0xffffu);
        a3 += bf2f(p.y >> 16);
    }
    float inv = invdeg[gw];
    unsigned short* hp = hb + (size_t)gw * 256 + lane * 4;
    uint2 h = *(uint2*)hp;
    a0 = a0 * inv + bf2f(h.x & 0xffffu);
    a1 = a1 * inv + bf2f(h.x >> 16);
    a2 = a2 * inv + bf2f(h.y & 0xffffu);
    a3 = a3 * inv + bf2f(h.y >> 16);
    uint2 o;
    o.x = f2bf(a0) | (f2bf(a1) << 16);
    o.y = f2bf(a2) | (f2bf(a3) << 16);
    *(uint2*)hp = o;
}

// ---- layer-0 SSM recurrence: state = first ? h*B : lam*state + h*B (bf16) ----
__global__ void ssm_update_kernel(unsigned short* __restrict__ state,
                                  const unsigned short* __restrict__ hb,
                                  const float* __restrict__ lam, const float* __restrict__ Bm,
                                  int first) {
    int tid = blockIdx.x * blockDim.x + threadIdx.x;
    if (tid >= V_DIM * 512) return;
    int i8 = tid * 8;
    int v = i8 >> 12;
    int k0 = i8 & 4095;
    float hv = bf2f((unsigned int)hb[(size_t)v * 256 + (k0 >> 4)]);
    floatx4 bm0 = *(const floatx4*)(Bm + k0);
    floatx4 bm1 = *(const floatx4*)(Bm + k0 + 4);
    float sv[8];
    if (first) {
#pragma unroll
        for (int j = 0; j < 4; ++j) { sv[j] = hv * bm0[j]; sv[4+j] = hv * bm1[j]; }
    } else {
        floatx4 lm0 = *(const floatx4*)(lam + k0);
        floatx4 lm1 = *(const floatx4*)(lam + k0 + 4);
        short8 s = *(const short8*)(state + (size_t)v * 4096 + k0);
#pragma unroll
        for (int j = 0; j < 4; ++j) {
            sv[j]   = lm0[j] * bf2f((unsigned int)(unsigned short)s[j])   + hv * bm0[j];
            sv[4+j] = lm1[j] * bf2f((unsigned int)(unsigned short)s[4+j]) + hv * bm1[j];
        }
    }
    uint4 pk;
    pk.x = f2bf(sv[0]) | (f2bf(sv[1]) << 16);
    pk.y = f2bf(sv[2]) | (f2bf(sv[3]) << 16);
    pk.z = f2bf(sv[4]) | (f2bf(sv[5]) << 16);
    pk.w = f2bf(sv[6]) | (f2bf(sv[7]) << 16);
    *(uint4*)(state + (size_t)v * 4096 + k0) = pk;
}

// ---- layer-1 closed-form final state ----
__global__ void state_eval_kernel(const unsigned short* __restrict__ hT, const float* __restrict__ C1,
                                  unsigned short* __restrict__ state) {
    int tid = blockIdx.x * blockDim.x + threadIdx.x;
    if (tid >= V_DIM * 512) return;
    int v = tid >> 9;
    int k0 = (tid & 511) * 8;
    int hh = k0 >> 4;
    float hv[8];
#pragma unroll
    for (int tau = 0; tau < 8; ++tau)
        hv[tau] = bf2f((unsigned int)hT[((size_t)tau * V_DIM + v) * 256 + hh]);
    float s[8];
#pragma unroll
    for (int j = 0; j < 8; ++j) s[j] = 0.f;
#pragma unroll
    for (int tau = 0; tau < 8; ++tau) {
        floatx4 c0 = *(const floatx4*)(C1 + tau * 4096 + k0);
        floatx4 c1 = *(const floatx4*)(C1 + tau * 4096 + k0 + 4);
#pragma unroll
        for (int j = 0; j < 4; ++j) { s[j] += hv[tau] * c0[j]; s[4 + j] += hv[tau] * c1[j]; }
    }
    uint4 pk;
    pk.x = f2bf(s[0]) | (f2bf(s[1]) << 16);
    pk.y = f2bf(s[2]) | (f2bf(s[3]) << 16);
    pk.z = f2bf(s[4]) | (f2bf(s[5]) << 16);
    pk.w = f2bf(s[6]) | (f2bf(s[7]) << 16);
    *(uint4*)(state + (size_t)v * 4096 + k0) = pk;
}

// ---- concat GEMM: x(t) @ [w_res|w_self|w_neigh] -> xsr(f32), h_self(bf16), xn(bf16)
__global__ __launch_bounds__(256)
void gemm_cat_kernel(const unsigned short* __restrict__ A, const unsigned short* __restrict__ Bp,
                     const float* __restrict__ bias, float* __restrict__ d0,
                     unsigned short* __restrict__ d1, unsigned short* __restrict__ d2,
                     int M, int K) {
    const int w = threadIdx.x >> 6, lane = threadIdx.x & 63;
    const int quad = lane >> 4, l16 = lane & 15;
    const int m0 = blockIdx.y * 64 + w * 16;
    const int ntb = blockIdx.x * 4;
    floatx4 acc[4];
#pragma unroll
    for (int i = 0; i < 4; ++i) acc[i] = (floatx4){0.f,0.f,0.f,0.f};
    int r = m0 + l16; if (r > M - 1) r = M - 1;
    const unsigned short* arow = A + (size_t)r * K + quad * 8;
    const int ksteps = K >> 5;
    for (int kt = 0; kt < ksteps; ++kt) {
        short8 af = *(const short8*)(arow + kt * 32);
#pragma unroll
        for (int i = 0; i < 4; ++i) {
            short8 bf = *(const short8*)(Bp + ((size_t)(kt * 48 + ntb + i) * 64 + lane) * 8);
            acc[i] = __builtin_amdgcn_mfma_f32_16x16x32_bf16(af, bf, acc[i], 0, 0, 0);
        }
    }
    const int region = blockIdx.x >> 2;
    const int rbase = m0 + quad * 4;
#pragma unroll
    for (int i = 0; i < 4; ++i) {
        int col = (ntb + i) * 16 + l16;
        int lcol = col & 255;
        float b = bias[col];
#pragma unroll
        for (int rr = 0; rr < 4; ++rr) {
            int row = rbase + rr;
            if (row < M) {
                float v = acc[i][rr] + b;
                size_t off = (size_t)row * 256 + lcol;
                if (region == 0) d0[off] = v;
                else if (region == 1) d1[off] = (unsigned short)f2bf(v);
                else d2[off] = (unsigned short)f2bf(v);
            }
        }
    }
}

// ---- high-occupancy GEMM: 32-row blocks, 8 waves (2 rowgroups x 4 n-chunks) ----
template<int NT, int NTN_TOT, bool RELU, bool RESID, bool BF16OUT>
__global__ __launch_bounds__(512)
void gemm16_kernel(const unsigned short* __restrict__ A, const unsigned short* __restrict__ Bp,
                   const float* __restrict__ bias, const float* __restrict__ resid,
                   float* __restrict__ outF, unsigned short* __restrict__ outB,
                   int M, int K) {
    const int w = threadIdx.x >> 6, lane = threadIdx.x & 63;
    const int quad = lane >> 4, l16 = lane & 15;
    const int rowgrp = w >> 2, nchunk = w & 3;
    const int m0 = blockIdx.x * 32 + rowgrp * 16;
    const int ntb = nchunk * NT;
    constexpr int Ntot = NTN_TOT * 16;
    floatx4 acc[NT];
#pragma unroll
    for (int i = 0; i < NT; ++i) acc[i] = (floatx4){0.f,0.f,0.f,0.f};
    int r = m0 + l16; if (r > M - 1) r = M - 1;
    const unsigned short* arow = A + (size_t)r * K + quad * 8;
    const int ksteps = K >> 5;
    for (int kt = 0; kt < ksteps; ++kt) {
        short8 af = *(const short8*)(arow + kt * 32);
        if (RELU) {
#pragma unroll
            for (int j = 0; j < 8; ++j) {
                short s = af[j];
                af[j] = (s < 0) ? (short)0 : s;
            }
        }
#pragma unroll
        for (int i = 0; i < NT; ++i) {
            short8 bf = *(const short8*)(Bp + ((size_t)(kt * NTN_TOT + ntb + i) * 64 + lane) * 8);
            acc[i] = __builtin_amdgcn_mfma_f32_16x16x32_bf16(af, bf, acc[i], 0, 0, 0);
        }
    }
    const int rbase = m0 + quad * 4;
#pragma unroll
    for (int i = 0; i < NT; ++i) {
        int col = (ntb + i) * 16 + l16;
        float b = bias[col];
#pragma unroll
        for (int rr = 0; rr < 4; ++rr) {
            int row = rbase + rr;
            if (row < M) {
                size_t off = (size_t)row * Ntot + col;
                float v = acc[i][rr] + b;
                if (RESID) v += resid[off];
                if (BF16OUT) outB[off] = (unsigned short)f2bf(v);
                else outF[off] = v;
            }
        }
    }
}

extern "C" void kernel_launch(void* const* d_in, const int* in_sizes, int n_in,
                              void* d_out, int out_size, void* d_ws, size_t ws_size,
                              hipStream_t stream) {
    const float* xs      = (const float*)d_in[0];
    const int*   ei      = (const int*)d_in[1];
    const float* w_pre   = (const float*)d_in[2];
    const float* b_pre   = (const float*)d_in[3];
    const float* w_res0  = (const float*)d_in[4];
    const float* b_res0  = (const float*)d_in[5];
    const float* w_self0 = (const float*)d_in[6];
    const float* w_neigh0= (const float*)d_in[7];
    const float* b_sage0 = (const float*)d_in[8];
    const float* a_log0  = (const float*)d_in[9];
    const float* B0      = (const float*)d_in[10];
    const float* w_mix0  = (const float*)d_in[11];
    const float* b_mix0  = (const float*)d_in[12];
    const float* w_res1  = (const float*)d_in[13];
    const float* b_res1  = (const float*)d_in[14];
    const float* w_self1 = (const float*)d_in[15];
    const float* w_neigh1= (const float*)d_in[16];
    const float* b_sage1 = (const float*)d_in[17];
    const float* a_log1  = (const float*)d_in[18];
    const float* B1      = (const float*)d_in[19];
    const float* w_mix1  = (const float*)d_in[20];
    const float* b_mix1  = (const float*)d_in[21];
    const float* w_out   = (const float*)d_in[22];
    const float* b_out   = (const float*)d_in[23];

    char* wsB = (char*)d_ws;
    size_t off = 0;
    auto alloc = [&](size_t bytes) {
        char* p = wsB + off;
        off += (bytes + 255) & ~(size_t)255;
        return p;
    };
    unsigned short* x0b   = (unsigned short*)alloc((size_t)T_DIM * V_DIM * 128 * 2);
    unsigned short* x1b   = (unsigned short*)alloc((size_t)T_DIM * V_DIM * 256 * 2);
    unsigned short* hT_b  = (unsigned short*)alloc((size_t)T_DIM * V_DIM * 256 * 2);
    unsigned short* hb_t  = (unsigned short*)alloc((size_t)V_DIM * 256 * 2);
    unsigned short* xn_t  = (unsigned short*)alloc((size_t)V_DIM * 256 * 2);
    float*          xsr_t = (float*)alloc((size_t)V_DIM * 256 * 4);
    unsigned short* state = (unsigned short*)alloc((size_t)V_DIM * 4096 * 2);
    unsigned short* out1_b= (unsigned short*)alloc((size_t)V_DIM * 256 * 2);
    int*            deg_cnt = (int*)alloc((size_t)T_DIM * V_DIM * 4);
    float*          invdeg  = (float*)alloc((size_t)T_DIM * V_DIM * 4);
    int*            rowptr  = (int*)alloc((size_t)T_DIM * (V_DIM + 1) * 4);
    int*            fill_cnt= (int*)alloc((size_t)T_DIM * V_DIM * 4);
    int*            srcs    = (int*)alloc((size_t)T_DIM * E_DIM * 4);
    float*          lam0  = (float*)alloc(4096 * 4);
    float*          C1    = (float*)alloc(8 * 4096 * 4);
    float*          bcat0 = (float*)alloc(768 * 4);
    float*          bcat1 = (float*)alloc(768 * 4);
    unsigned short* wcat0p= (unsigned short*)alloc((size_t)128 * 768 * 2);
    unsigned short* wcat1p= (unsigned short*)alloc((size_t)256 * 768 * 2);
    unsigned short* wmix0p= (unsigned short*)alloc((size_t)4096 * 256 * 2);
    unsigned short* wmix1p= (unsigned short*)alloc((size_t)4096 * 256 * 2);
    unsigned short* woutp = (unsigned short*)alloc((size_t)256 * 64 * 2);
    if (off > ws_size) return;   // fail cleanly, not a GPU fault

    auto cdiv = [](int a, int b) { return (a + b - 1) / b; };

    // ---- parameter prep ----
    lamC_kernel<<<16, 256, 0, stream>>>(a_log0, a_log1, B1, lam0, C1);
    bias_cat_kernel<<<3, 256, 0, stream>>>(b_res0, b_sage0, b_res1, b_sage1, bcat0, bcat1);
    pack_b_kernel<<<cdiv(4*16*64, 256), 256, 0, stream>>>(w_res0,   wcat0p, 128, 256, 48, 0);
    pack_b_kernel<<<cdiv(4*16*64, 256), 256, 0, stream>>>(w_self0,  wcat0p, 128, 256, 48, 16);
    pack_b_kernel<<<cdiv(4*16*64, 256), 256, 0, stream>>>(w_neigh0, wcat0p, 128, 256, 48, 32);
    pack_b_kernel<<<cdiv(8*16*64, 256), 256, 0, stream>>>(w_res1,   wcat1p, 256, 256, 48, 0);
    pack_b_kernel<<<cdiv(8*16*64, 256), 256, 0, stream>>>(w_self1,  wcat1p, 256, 256, 48, 16);
    pack_b_kernel<<<cdiv(8*16*64, 256), 256, 0, stream>>>(w_neigh1, wcat1p, 256, 256, 48, 32);
    pack_b_kernel<<<cdiv(128*16*64, 256), 256, 0, stream>>>(w_mix0, wmix0p, 4096, 256, 16, 0);
    pack_b_kernel<<<cdiv(128*16*64, 256), 256, 0, stream>>>(w_mix1, wmix1p, 4096, 256, 16, 0);
    pack_b_kernel<<<cdiv(8*4*64, 256), 256, 0, stream>>>(w_out, woutp, 256, 64, 4, 0);

    // ---- token mixer + CSR build ----
    token_mix_kernel<<<cdiv(T_DIM*V_DIM*128/4, 256), 256, 0, stream>>>(xs, w_pre, b_pre, x0b);
    hipMemsetAsync(deg_cnt, 0, (size_t)T_DIM * V_DIM * 4, stream);
    hipMemsetAsync(fill_cnt, 0, (size_t)T_DIM * V_DIM * 4, stream);
    deg_kernel<<<cdiv(T_DIM*E_DIM, 256), 256, 0, stream>>>(ei, deg_cnt);
    scan_kernel<<<T_DIM, 1024, 0, stream>>>(deg_cnt, rowptr);
    invdeg_kernel<<<cdiv(T_DIM*V_DIM, 256), 256, 0, stream>>>(deg_cnt, invdeg);
    fill_kernel<<<cdiv(T_DIM*E_DIM, 256), 256, 0, stream>>>(ei, rowptr, fill_cnt, srcs);

    const int gCat = cdiv(V_DIM, 64);    // 157
    const int g16  = cdiv(V_DIM, 32);    // 313
    const int gGat = cdiv(V_DIM * 64, 256);

    // ================= LAYER 0 =================
    for (int t = 0; t < T_DIM; ++t) {
        gemm_cat_kernel<<<dim3(12, gCat), 256, 0, stream>>>(
            x0b + (size_t)t * V_DIM * 128, wcat0p, bcat0, xsr_t, hb_t, xn_t, V_DIM, 128);
        gather_kernel<<<gGat, 256, 0, stream>>>(
            xn_t, srcs + (size_t)t * E_DIM, rowptr + (size_t)t * (V_DIM + 1),
            invdeg + (size_t)t * V_DIM, hb_t);
        ssm_update_kernel<<<cdiv(V_DIM*512, 256), 256, 0, stream>>>(
            state, hb_t, lam0, B0, t == 0 ? 1 : 0);
        gemm16_kernel<4, 16, true, true, true><<<g16, 512, 0, stream>>>(
            state, wmix0p, b_mix0, xsr_t, nullptr, x1b + (size_t)t * V_DIM * 256, V_DIM, 4096);
    }

    // ================= LAYER 1 =================
    for (int t = 0; t < T_DIM; ++t) {
        gemm_cat_kernel<<<dim3(12, gCat), 256, 0, stream>>>(
            x1b + (size_t)t * V_DIM * 256, wcat1p, bcat1, xsr_t,
            hT_b + (size_t)t * V_DIM * 256, xn_t, V_DIM, 256);
        gather_kernel<<<gGat, 256, 0, stream>>>(
            xn_t, srcs + (size_t)t * E_DIM, rowptr + (size_t)t * (V_DIM + 1),
            invdeg + (size_t)t * V_DIM, hT_b + (size_t)t * V_DIM * 256);
    }
    state_eval_kernel<<<cdiv(V_DIM*512, 256), 256, 0, stream>>>(hT_b, C1, state);
    gemm16_kernel<4, 16, true, true, true><<<g16, 512, 0, stream>>>(
        state, wmix1p, b_mix1, xsr_t, nullptr, out1_b, V_DIM, 4096);

    // ================= head =================
    gemm16_kernel<1, 4, false, false, false><<<g16, 512, 0, stream>>>(
        out1_b, woutp, b_out, nullptr, (float*)d_out, nullptr, V_DIM, 256);
}

// Round 4
// 1822.252 us; speedup vs baseline: 7.9829x; 1.2089x over previous
//
#include <hip/hip_runtime.h>
#include <cstdint>
#include <cstddef>

#define T_DIM 8
#define V_DIM 10000
#define E_DIM 100000

typedef __attribute__((ext_vector_type(8))) short short8;
typedef __attribute__((ext_vector_type(4))) float floatx4;

__device__ __forceinline__ unsigned int f2bf(float f) {
    union { float f; unsigned int u; } v; v.f = f;
    unsigned int u = v.u;
    u = u + 0x7FFFu + ((u >> 16) & 1u);   // RNE
    return u >> 16;
}
__device__ __forceinline__ float bf2f(unsigned int s) {
    union { unsigned int u; float f; } v; v.u = s << 16;
    return v.f;
}
__device__ __forceinline__ short8 relu8(short8 x) {
    const short8 z = {0,0,0,0,0,0,0,0};
    return __builtin_elementwise_max(x, z);   // v_pk_max_i16: bf16 relu on bit pattern
}

// ---- pack fp32 weight [K,Nw] into MFMA B-fragment order inside a concat buffer
__global__ void pack_b_kernel(const float* __restrict__ w, unsigned short* __restrict__ out,
                              int K, int Nw, int NTN_tot, int nt_off) {
    int tid = blockIdx.x * blockDim.x + threadIdx.x;
    int total = (K >> 5) * (Nw >> 4) * 64;
    if (tid >= total) return;
    int lane = tid & 63;
    int f = tid >> 6;
    int ntn_w = Nw >> 4;
    int nt = f % ntn_w;
    int kt = f / ntn_w;
    int kbase = kt * 32 + ((lane >> 4) << 3);
    int n = nt * 16 + (lane & 15);
    unsigned int vals[8];
#pragma unroll
    for (int j = 0; j < 8; ++j)
        vals[j] = f2bf(w[(size_t)(kbase + j) * Nw + n]);
    uint4 pk;
    pk.x = vals[0] | (vals[1] << 16);
    pk.y = vals[2] | (vals[3] << 16);
    pk.z = vals[4] | (vals[5] << 16);
    pk.w = vals[6] | (vals[7] << 16);
    size_t fo = (size_t)kt * NTN_tot + nt_off + nt;
    *(uint4*)(out + (fo * 64 + lane) * 8) = pk;
}

// ---- token mixer ----
__global__ void token_mix_kernel(const float* __restrict__ xs, const float* __restrict__ w_pre,
                                 const float* __restrict__ b_pre, unsigned short* __restrict__ ob) {
    const int S = V_DIM * 128;
    int tid = blockIdx.x * blockDim.x + threadIdx.x;
    if (tid >= T_DIM * S / 4) return;
    int e = tid * 4;
    int t = e / S;
    int c = e & 127;
    floatx4 xm = {0.f,0.f,0.f,0.f}, xp = {0.f,0.f,0.f,0.f};
    floatx4 x0 = *(const floatx4*)(xs + e);
    if (t > 0)          xm = *(const floatx4*)(xs + e - S);
    if (t < T_DIM - 1)  xp = *(const floatx4*)(xs + e + S);
    uint2 p; unsigned int b[4];
#pragma unroll
    for (int j = 0; j < 4; ++j) {
        int cc = c + j;
        float r = xm[j]*w_pre[cc*3+0] + x0[j]*w_pre[cc*3+1] + xp[j]*w_pre[cc*3+2] + b_pre[cc];
        b[j] = f2bf(r);
    }
    p.x = b[0] | (b[1] << 16);
    p.y = b[2] | (b[3] << 16);
    *(uint2*)(ob + e) = p;
}

// ---- lam0 = exp(-exp(a0)); C1[tau,kk] = B1[kk]*lam1^(7-tau) ----
__global__ void lamC_kernel(const float* __restrict__ a0, const float* __restrict__ a1,
                            const float* __restrict__ B1, float* __restrict__ lam0,
                            float* __restrict__ C1) {
    int i = blockIdx.x * blockDim.x + threadIdx.x;
    if (i >= 4096) return;
    lam0[i] = expf(-expf(a0[i]));
    float l1 = expf(-expf(a1[i]));
    float pw = B1[i];
    for (int tau = 7; tau >= 0; --tau) { C1[tau * 4096 + i] = pw; pw *= l1; }
}

__global__ void bias_cat_kernel(const float* __restrict__ br0, const float* __restrict__ bs0,
                                const float* __restrict__ br1, const float* __restrict__ bs1,
                                float* __restrict__ bcat0, float* __restrict__ bcat1) {
    int i = blockIdx.x * blockDim.x + threadIdx.x;
    if (i >= 768) return;
    bcat0[i] = (i < 256) ? br0[i] : (i < 512 ? bs0[i - 256] : 0.f);
    bcat1[i] = (i < 256) ? br1[i] : (i < 512 ? bs1[i - 256] : 0.f);
}

// ================= CSR build =================
__global__ void deg_kernel(const int* __restrict__ ei, int* __restrict__ deg_cnt) {
    int tid = blockIdx.x * blockDim.x + threadIdx.x;
    if (tid >= T_DIM * E_DIM) return;
    int t = tid / E_DIM;
    int e = tid - t * E_DIM;
    int dst = ei[(size_t)t * 2 * E_DIM + E_DIM + e];
    if ((unsigned)dst < V_DIM) atomicAdd(deg_cnt + t * V_DIM + dst, 1);
}

__global__ void invdeg_kernel(const int* __restrict__ deg_cnt, float* __restrict__ inv) {
    int tid = blockIdx.x * blockDim.x + threadIdx.x;
    if (tid >= T_DIM * V_DIM) return;
    inv[tid] = 1.0f / (float)max(deg_cnt[tid], 1);
}

__global__ __launch_bounds__(1024)
void scan_kernel(const int* __restrict__ deg_cnt, int* __restrict__ rowptr) {
    __shared__ int sums[1024];
    int t = blockIdx.x;
    const int* d = deg_cnt + t * V_DIM;
    int* rp = rowptr + t * (V_DIM + 1);
    int tid = threadIdx.x;
    int base = tid * 10;
    int loc[10]; int s = 0;
#pragma unroll
    for (int j = 0; j < 10; ++j) {
        int v = base + j;
        int x = (v < V_DIM) ? d[v] : 0;
        loc[j] = s; s += x;
    }
    sums[tid] = s;
    __syncthreads();
    for (int o = 1; o < 1024; o <<= 1) {
        int v = (tid >= o) ? sums[tid - o] : 0;
        __syncthreads();
        sums[tid] += v;
        __syncthreads();
    }
    int prev = (tid == 0) ? 0 : sums[tid - 1];
#pragma unroll
    for (int j = 0; j < 10; ++j) {
        int v = base + j;
        if (v < V_DIM) rp[v] = prev + loc[j];
    }
    if (tid == 1023) rp[V_DIM] = sums[1023];
}

__global__ void fill_kernel(const int* __restrict__ ei, const int* __restrict__ rowptr,
                            int* __restrict__ fill_cnt, int* __restrict__ srcs) {
    int tid = blockIdx.x * blockDim.x + threadIdx.x;
    if (tid >= T_DIM * E_DIM) return;
    int t = tid / E_DIM;
    int e = tid - t * E_DIM;
    const int* eit = ei + (size_t)t * 2 * E_DIM;
    int src = eit[e];
    int dst = eit[E_DIM + e];
    if ((unsigned)src >= V_DIM || (unsigned)dst >= V_DIM) return;
    int pos = rowptr[t * (V_DIM + 1) + dst] + atomicAdd(fill_cnt + t * V_DIM + dst, 1);
    srcs[(size_t)t * E_DIM + pos] = src;
}

// ---- gather: hb[v] += (sum_{src in bucket(v)} xn[src]) * invdeg[v]; one wave per v
__global__ void gather_kernel(const unsigned short* __restrict__ xn, const int* __restrict__ srcs,
                              const int* __restrict__ rowptr, const float* __restrict__ invdeg,
                              unsigned short* __restrict__ hb) {
    int gw = (blockIdx.x * blockDim.x + threadIdx.x) >> 6;
    int lane = threadIdx.x & 63;
    if (gw >= V_DIM) return;
    int beg = rowptr[gw], end = rowptr[gw + 1];
    float a0 = 0.f, a1 = 0.f, a2 = 0.f, a3 = 0.f;
    for (int i = beg; i < end; ++i) {
        int s = srcs[i];
        uint2 p = *(const uint2*)(xn + (size_t)s * 256 + lane * 4);
        a0 += bf2f(p.x & 0xffffu);
        a1 += bf2f(p.x >> 16);
        a2 += bf2f(p.y & 0xffffu);
        a3 += bf2f(p.y >> 16);
    }
    float inv = invdeg[gw];
    unsigned short* hp = hb + (size_t)gw * 256 + lane * 4;
    uint2 h = *(uint2*)hp;
    a0 = a0 * inv + bf2f(h.x & 0xffffu);
    a1 = a1 * inv + bf2f(h.x >> 16);
    a2 = a2 * inv + bf2f(h.y & 0xffffu);
    a3 = a3 * inv + bf2f(h.y >> 16);
    uint2 o;
    o.x = f2bf(a0) | (f2bf(a1) << 16);
    o.y = f2bf(a2) | (f2bf(a3) << 16);
    *(uint2*)hp = o;
}

// ---- layer-0 SSM recurrence: state = first ? h*B : lam*state + h*B (bf16) ----
__global__ void ssm_update_kernel(unsigned short* __restrict__ state,
                                  const unsigned short* __restrict__ hb,
                                  const float* __restrict__ lam, const float* __restrict__ Bm,
                                  int first) {
    int tid = blockIdx.x * blockDim.x + threadIdx.x;
    if (tid >= V_DIM * 512) return;
    int i8 = tid * 8;
    int v = i8 >> 12;
    int k0 = i8 & 4095;
    float hv = bf2f((unsigned int)hb[(size_t)v * 256 + (k0 >> 4)]);
    floatx4 bm0 = *(const floatx4*)(Bm + k0);
    floatx4 bm1 = *(const floatx4*)(Bm + k0 + 4);
    float sv[8];
    if (first) {
#pragma unroll
        for (int j = 0; j < 4; ++j) { sv[j] = hv * bm0[j]; sv[4+j] = hv * bm1[j]; }
    } else {
        floatx4 lm0 = *(const floatx4*)(lam + k0);
        floatx4 lm1 = *(const floatx4*)(lam + k0 + 4);
        short8 s = *(const short8*)(state + (size_t)v * 4096 + k0);
#pragma unroll
        for (int j = 0; j < 4; ++j) {
            sv[j]   = lm0[j] * bf2f((unsigned int)(unsigned short)s[j])   + hv * bm0[j];
            sv[4+j] = lm1[j] * bf2f((unsigned int)(unsigned short)s[4+j]) + hv * bm1[j];
        }
    }
    uint4 pk;
    pk.x = f2bf(sv[0]) | (f2bf(sv[1]) << 16);
    pk.y = f2bf(sv[2]) | (f2bf(sv[3]) << 16);
    pk.z = f2bf(sv[4]) | (f2bf(sv[5]) << 16);
    pk.w = f2bf(sv[6]) | (f2bf(sv[7]) << 16);
    *(uint4*)(state + (size_t)v * 4096 + k0) = pk;
}

// ---- layer-1 closed-form final state ----
__global__ void state_eval_kernel(const unsigned short* __restrict__ hT, const float* __restrict__ C1,
                                  unsigned short* __restrict__ state) {
    int tid = blockIdx.x * blockDim.x + threadIdx.x;
    if (tid >= V_DIM * 512) return;
    int v = tid >> 9;
    int k0 = (tid & 511) * 8;
    int hh = k0 >> 4;
    float hv[8];
#pragma unroll
    for (int tau = 0; tau < 8; ++tau)
        hv[tau] = bf2f((unsigned int)hT[((size_t)tau * V_DIM + v) * 256 + hh]);
    float s[8];
#pragma unroll
    for (int j = 0; j < 8; ++j) s[j] = 0.f;
#pragma unroll
    for (int tau = 0; tau < 8; ++tau) {
        floatx4 c0 = *(const floatx4*)(C1 + tau * 4096 + k0);
        floatx4 c1 = *(const floatx4*)(C1 + tau * 4096 + k0 + 4);
#pragma unroll
        for (int j = 0; j < 4; ++j) { s[j] += hv[tau] * c0[j]; s[4 + j] += hv[tau] * c1[j]; }
    }
    uint4 pk;
    pk.x = f2bf(s[0]) | (f2bf(s[1]) << 16);
    pk.y = f2bf(s[2]) | (f2bf(s[3]) << 16);
    pk.z = f2bf(s[4]) | (f2bf(s[5]) << 16);
    pk.w = f2bf(s[6]) | (f2bf(s[7]) << 16);
    *(uint4*)(state + (size_t)v * 4096 + k0) = pk;
}

// ---- cat GEMM, 4 m-tiles/wave: block = 64 rows x 256 cols of one region ----
// grid (3 regions, 157); wave w covers cols w*64 within region; B-frags reused x4 m-tiles
template<int KT>   // k-steps: K/32
__global__ __launch_bounds__(256, 4)
void gemm_cat2_kernel(const unsigned short* __restrict__ A, const unsigned short* __restrict__ Bp,
                      const float* __restrict__ bias, float* __restrict__ d0,
                      unsigned short* __restrict__ d1, unsigned short* __restrict__ d2, int M) {
    const int w = threadIdx.x >> 6, lane = threadIdx.x & 63;
    const int quad = lane >> 4, l16 = lane & 15;
    const int region = blockIdx.x;
    const int m0 = blockIdx.y * 64;
    constexpr int K = KT * 32;
    floatx4 acc[4][4];
#pragma unroll
    for (int a = 0; a < 4; ++a)
#pragma unroll
        for (int b = 0; b < 4; ++b) acc[a][b] = (floatx4){0.f,0.f,0.f,0.f};
    const unsigned short* arow[4];
#pragma unroll
    for (int mi = 0; mi < 4; ++mi) {
        int r = m0 + mi * 16 + l16;
        if (r > M - 1) r = M - 1;
        arow[mi] = A + (size_t)r * K + quad * 8;
    }
    const unsigned short* bptr = Bp + ((size_t)(region * 16 + w * 4) * 64 + lane) * 8;
#pragma unroll
    for (int kt = 0; kt < KT; ++kt) {
        short8 bfr[4];
#pragma unroll
        for (int i = 0; i < 4; ++i) bfr[i] = *(const short8*)(bptr + i * 512);
        short8 af[4];
#pragma unroll
        for (int mi = 0; mi < 4; ++mi) af[mi] = *(const short8*)(arow[mi]);
#pragma unroll
        for (int mi = 0; mi < 4; ++mi)
#pragma unroll
            for (int i = 0; i < 4; ++i)
                acc[mi][i] = __builtin_amdgcn_mfma_f32_16x16x32_bf16(af[mi], bfr[i], acc[mi][i], 0, 0, 0);
        bptr += 48 * 512;
#pragma unroll
        for (int mi = 0; mi < 4; ++mi) arow[mi] += 32;
    }
#pragma unroll
    for (int mi = 0; mi < 4; ++mi) {
        int rbase = m0 + mi * 16 + quad * 4;
#pragma unroll
        for (int i = 0; i < 4; ++i) {
            int lcol = w * 64 + i * 16 + l16;
            float b = bias[region * 256 + lcol];
#pragma unroll
            for (int rr = 0; rr < 4; ++rr) {
                int row = rbase + rr;
                if (row < M) {
                    float v = acc[mi][i][rr] + b;
                    size_t off = (size_t)row * 256 + lcol;
                    if (region == 0) d0[off] = v;
                    else if (region == 1) d1[off] = (unsigned short)f2bf(v);
                    else d2[off] = (unsigned short)f2bf(v);
                }
            }
        }
    }
}

// ---- split-K mix GEMM: part[ks] = relu(state[:, ks*KS*32 .. ]) @ Wp_slice ----
// grid (4 splits, 157); block 64 rows x 256 cols; wave = 64 rows x 64 cols
template<int KSLICE>
__global__ __launch_bounds__(256, 4)
void gemm_mix_kernel(const unsigned short* __restrict__ A, const unsigned short* __restrict__ Bp,
                     float* __restrict__ part, int M) {
    const int w = threadIdx.x >> 6, lane = threadIdx.x & 63;
    const int quad = lane >> 4, l16 = lane & 15;
    const int ks = blockIdx.x;
    const int m0 = blockIdx.y * 64;
    floatx4 acc[4][4];
#pragma unroll
    for (int a = 0; a < 4; ++a)
#pragma unroll
        for (int b = 0; b < 4; ++b) acc[a][b] = (floatx4){0.f,0.f,0.f,0.f};
    const unsigned short* arow[4];
#pragma unroll
    for (int mi = 0; mi < 4; ++mi) {
        int r = m0 + mi * 16 + l16;
        if (r > M - 1) r = M - 1;
        arow[mi] = A + (size_t)r * 4096 + ks * (KSLICE * 32) + quad * 8;
    }
    const unsigned short* bptr = Bp + ((size_t)(ks * KSLICE * 16 + w * 4) * 64 + lane) * 8;
    for (int kt = 0; kt < KSLICE; ++kt) {
        short8 bfr[4];
#pragma unroll
        for (int i = 0; i < 4; ++i) bfr[i] = *(const short8*)(bptr + i * 512);
        short8 af[4];
#pragma unroll
        for (int mi = 0; mi < 4; ++mi) af[mi] = relu8(*(const short8*)(arow[mi]));
#pragma unroll
        for (int mi = 0; mi < 4; ++mi)
#pragma unroll
            for (int i = 0; i < 4; ++i)
                acc[mi][i] = __builtin_amdgcn_mfma_f32_16x16x32_bf16(af[mi], bfr[i], acc[mi][i], 0, 0, 0);
        bptr += 16 * 512;
#pragma unroll
        for (int mi = 0; mi < 4; ++mi) arow[mi] += 32;
    }
#pragma unroll
    for (int mi = 0; mi < 4; ++mi) {
        int rbase = m0 + mi * 16 + quad * 4;
#pragma unroll
        for (int i = 0; i < 4; ++i) {
            int col = w * 64 + i * 16 + l16;
#pragma unroll
            for (int rr = 0; rr < 4; ++rr) {
                int row = rbase + rr;
                if (row < M)
                    part[((size_t)ks * M + row) * 256 + col] = acc[mi][i][rr];
            }
        }
    }
}

// ---- reduce 4 split-K partials + bias + resid -> bf16 ----
__global__ void reduce4_kernel(const float* __restrict__ part, const float* __restrict__ bias,
                               const float* __restrict__ resid, unsigned short* __restrict__ out, int M) {
    int tid = blockIdx.x * blockDim.x + threadIdx.x;
    if (tid >= M * 64) return;
    size_t i4 = (size_t)tid * 4;
    const size_t S = (size_t)M * 256;
    floatx4 s = *(const floatx4*)(part + i4);
    floatx4 s1 = *(const floatx4*)(part + S + i4);
    floatx4 s2 = *(const floatx4*)(part + 2 * S + i4);
    floatx4 s3 = *(const floatx4*)(part + 3 * S + i4);
    floatx4 rv = *(const floatx4*)(resid + i4);
    floatx4 bv = *(const floatx4*)(bias + (i4 & 255));
    uint2 o;
    float v0 = s[0] + s1[0] + s2[0] + s3[0] + rv[0] + bv[0];
    float v1 = s[1] + s1[1] + s2[1] + s3[1] + rv[1] + bv[1];
    float v2 = s[2] + s1[2] + s2[2] + s3[2] + rv[2] + bv[2];
    float v3 = s[3] + s1[3] + s2[3] + s3[3] + rv[3] + bv[3];
    o.x = f2bf(v0) | (f2bf(v1) << 16);
    o.y = f2bf(v2) | (f2bf(v3) << 16);
    *(uint2*)(out + i4) = o;
}

// ---- small GEMM (head): 32-row blocks, 8 waves ----
template<int NT, int NTN_TOT, bool RELU, bool RESID, bool BF16OUT>
__global__ __launch_bounds__(512)
void gemm16_kernel(const unsigned short* __restrict__ A, const unsigned short* __restrict__ Bp,
                   const float* __restrict__ bias, const float* __restrict__ resid,
                   float* __restrict__ outF, unsigned short* __restrict__ outB,
                   int M, int K) {
    const int w = threadIdx.x >> 6, lane = threadIdx.x & 63;
    const int quad = lane >> 4, l16 = lane & 15;
    const int rowgrp = w >> 2, nchunk = w & 3;
    const int m0 = blockIdx.x * 32 + rowgrp * 16;
    const int ntb = nchunk * NT;
    constexpr int Ntot = NTN_TOT * 16;
    floatx4 acc[NT];
#pragma unroll
    for (int i = 0; i < NT; ++i) acc[i] = (floatx4){0.f,0.f,0.f,0.f};
    int r = m0 + l16; if (r > M - 1) r = M - 1;
    const unsigned short* arow = A + (size_t)r * K + quad * 8;
    const int ksteps = K >> 5;
    for (int kt = 0; kt < ksteps; ++kt) {
        short8 af = *(const short8*)(arow + kt * 32);
        if (RELU) af = relu8(af);
#pragma unroll
        for (int i = 0; i < NT; ++i) {
            short8 bf = *(const short8*)(Bp + ((size_t)(kt * NTN_TOT + ntb + i) * 64 + lane) * 8);
            acc[i] = __builtin_amdgcn_mfma_f32_16x16x32_bf16(af, bf, acc[i], 0, 0, 0);
        }
    }
    const int rbase = m0 + quad * 4;
#pragma unroll
    for (int i = 0; i < NT; ++i) {
        int col = (ntb + i) * 16 + l16;
        float b = bias[col];
#pragma unroll
        for (int rr = 0; rr < 4; ++rr) {
            int row = rbase + rr;
            if (row < M) {
                size_t off = (size_t)row * Ntot + col;
                float v = acc[i][rr] + b;
                if (RESID) v += resid[off];
                if (BF16OUT) outB[off] = (unsigned short)f2bf(v);
                else outF[off] = v;
            }
        }
    }
}

extern "C" void kernel_launch(void* const* d_in, const int* in_sizes, int n_in,
                              void* d_out, int out_size, void* d_ws, size_t ws_size,
                              hipStream_t stream) {
    const float* xs      = (const float*)d_in[0];
    const int*   ei      = (const int*)d_in[1];
    const float* w_pre   = (const float*)d_in[2];
    const float* b_pre   = (const float*)d_in[3];
    const float* w_res0  = (const float*)d_in[4];
    const float* b_res0  = (const float*)d_in[5];
    const float* w_self0 = (const float*)d_in[6];
    const float* w_neigh0= (const float*)d_in[7];
    const float* b_sage0 = (const float*)d_in[8];
    const float* a_log0  = (const float*)d_in[9];
    const float* B0      = (const float*)d_in[10];
    const float* w_mix0  = (const float*)d_in[11];
    const float* b_mix0  = (const float*)d_in[12];
    const float* w_res1  = (const float*)d_in[13];
    const float* b_res1  = (const float*)d_in[14];
    const float* w_self1 = (const float*)d_in[15];
    const float* w_neigh1= (const float*)d_in[16];
    const float* b_sage1 = (const float*)d_in[17];
    const float* a_log1  = (const float*)d_in[18];
    const float* B1      = (const float*)d_in[19];
    const float* w_mix1  = (const float*)d_in[20];
    const float* b_mix1  = (const float*)d_in[21];
    const float* w_out   = (const float*)d_in[22];
    const float* b_out   = (const float*)d_in[23];

    char* wsB = (char*)d_ws;
    size_t off = 0;
    auto alloc = [&](size_t bytes) {
        char* p = wsB + off;
        off += (bytes + 255) & ~(size_t)255;
        return p;
    };
    unsigned short* x0b   = (unsigned short*)alloc((size_t)T_DIM * V_DIM * 128 * 2);
    unsigned short* x1b   = (unsigned short*)alloc((size_t)T_DIM * V_DIM * 256 * 2);
    unsigned short* hT_b  = (unsigned short*)alloc((size_t)T_DIM * V_DIM * 256 * 2);
    unsigned short* hb_t  = (unsigned short*)alloc((size_t)V_DIM * 256 * 2);
    unsigned short* xn_t  = (unsigned short*)alloc((size_t)V_DIM * 256 * 2);
    float*          xsr_t = (float*)alloc((size_t)V_DIM * 256 * 4);
    unsigned short* state = (unsigned short*)alloc((size_t)V_DIM * 4096 * 2);
    float*          part  = (float*)alloc((size_t)4 * V_DIM * 256 * 4);
    unsigned short* out1_b= (unsigned short*)alloc((size_t)V_DIM * 256 * 2);
    int*            deg_cnt = (int*)alloc((size_t)T_DIM * V_DIM * 4);
    float*          invdeg  = (float*)alloc((size_t)T_DIM * V_DIM * 4);
    int*            rowptr  = (int*)alloc((size_t)T_DIM * (V_DIM + 1) * 4);
    int*            fill_cnt= (int*)alloc((size_t)T_DIM * V_DIM * 4);
    int*            srcs    = (int*)alloc((size_t)T_DIM * E_DIM * 4);
    float*          lam0  = (float*)alloc(4096 * 4);
    float*          C1    = (float*)alloc(8 * 4096 * 4);
    float*          bcat0 = (float*)alloc(768 * 4);
    float*          bcat1 = (float*)alloc(768 * 4);
    unsigned short* wcat0p= (unsigned short*)alloc((size_t)128 * 768 * 2);
    unsigned short* wcat1p= (unsigned short*)alloc((size_t)256 * 768 * 2);
    unsigned short* wmix0p= (unsigned short*)alloc((size_t)4096 * 256 * 2);
    unsigned short* wmix1p= (unsigned short*)alloc((size_t)4096 * 256 * 2);
    unsigned short* woutp = (unsigned short*)alloc((size_t)256 * 64 * 2);
    if (off > ws_size) return;   // fail cleanly, not a GPU fault

    auto cdiv = [](int a, int b) { return (a + b - 1) / b; };

    // ---- parameter prep ----
    lamC_kernel<<<16, 256, 0, stream>>>(a_log0, a_log1, B1, lam0, C1);
    bias_cat_kernel<<<3, 256, 0, stream>>>(b_res0, b_sage0, b_res1, b_sage1, bcat0, bcat1);
    pack_b_kernel<<<cdiv(4*16*64, 256), 256, 0, stream>>>(w_res0,   wcat0p, 128, 256, 48, 0);
    pack_b_kernel<<<cdiv(4*16*64, 256), 256, 0, stream>>>(w_self0,  wcat0p, 128, 256, 48, 16);
    pack_b_kernel<<<cdiv(4*16*64, 256), 256, 0, stream>>>(w_neigh0, wcat0p, 128, 256, 48, 32);
    pack_b_kernel<<<cdiv(8*16*64, 256), 256, 0, stream>>>(w_res1,   wcat1p, 256, 256, 48, 0);
    pack_b_kernel<<<cdiv(8*16*64, 256), 256, 0, stream>>>(w_self1,  wcat1p, 256, 256, 48, 16);
    pack_b_kernel<<<cdiv(8*16*64, 256), 256, 0, stream>>>(w_neigh1, wcat1p, 256, 256, 48, 32);
    pack_b_kernel<<<cdiv(128*16*64, 256), 256, 0, stream>>>(w_mix0, wmix0p, 4096, 256, 16, 0);
    pack_b_kernel<<<cdiv(128*16*64, 256), 256, 0, stream>>>(w_mix1, wmix1p, 4096, 256, 16, 0);
    pack_b_kernel<<<cdiv(8*4*64, 256), 256, 0, stream>>>(w_out, woutp, 256, 64, 4, 0);

    // ---- token mixer + CSR build ----
    token_mix_kernel<<<cdiv(T_DIM*V_DIM*128/4, 256), 256, 0, stream>>>(xs, w_pre, b_pre, x0b);
    hipMemsetAsync(deg_cnt, 0, (size_t)T_DIM * V_DIM * 4, stream);
    hipMemsetAsync(fill_cnt, 0, (size_t)T_DIM * V_DIM * 4, stream);
    deg_kernel<<<cdiv(T_DIM*E_DIM, 256), 256, 0, stream>>>(ei, deg_cnt);
    scan_kernel<<<T_DIM, 1024, 0, stream>>>(deg_cnt, rowptr);
    invdeg_kernel<<<cdiv(T_DIM*V_DIM, 256), 256, 0, stream>>>(deg_cnt, invdeg);
    fill_kernel<<<cdiv(T_DIM*E_DIM, 256), 256, 0, stream>>>(ei, rowptr, fill_cnt, srcs);

    const int gM64 = cdiv(V_DIM, 64);    // 157
    const int gGat = cdiv(V_DIM * 64, 256);
    const int gRed = cdiv(V_DIM * 64, 256);

    // ================= LAYER 0 =================
    for (int t = 0; t < T_DIM; ++t) {
        gemm_cat2_kernel<4><<<dim3(3, gM64), 256, 0, stream>>>(
            x0b + (size_t)t * V_DIM * 128, wcat0p, bcat0, xsr_t, hb_t, xn_t, V_DIM);
        gather_kernel<<<gGat, 256, 0, stream>>>(
            xn_t, srcs + (size_t)t * E_DIM, rowptr + (size_t)t * (V_DIM + 1),
            invdeg + (size_t)t * V_DIM, hb_t);
        ssm_update_kernel<<<cdiv(V_DIM*512, 256), 256, 0, stream>>>(
            state, hb_t, lam0, B0, t == 0 ? 1 : 0);
        gemm_mix_kernel<32><<<dim3(4, gM64), 256, 0, stream>>>(state, wmix0p, part, V_DIM);
        reduce4_kernel<<<gRed, 256, 0, stream>>>(
            part, b_mix0, xsr_t, x1b + (size_t)t * V_DIM * 256, V_DIM);
    }

    // ================= LAYER 1 =================
    for (int t = 0; t < T_DIM; ++t) {
        gemm_cat2_kernel<8><<<dim3(3, gM64), 256, 0, stream>>>(
            x1b + (size_t)t * V_DIM * 256, wcat1p, bcat1, xsr_t,
            hT_b + (size_t)t * V_DIM * 256, xn_t, V_DIM);
        gather_kernel<<<gGat, 256, 0, stream>>>(
            xn_t, srcs + (size_t)t * E_DIM, rowptr + (size_t)t * (V_DIM + 1),
            invdeg + (size_t)t * V_DIM, hT_b + (size_t)t * V_DIM * 256);
    }
    state_eval_kernel<<<cdiv(V_DIM*512, 256), 256, 0, stream>>>(hT_b, C1, state);
    gemm_mix_kernel<32><<<dim3(4, gM64), 256, 0, stream>>>(state, wmix1p, part, V_DIM);
    reduce4_kernel<<<gRed, 256, 0, stream>>>(part, b_mix1, xsr_t, out1_b, V_DIM);

    // ================= head =================
    gemm16_kernel<1, 4, false, false, false><<<cdiv(V_DIM,32), 512, 0, stream>>>(
        out1_b, woutp, b_out, nullptr, (float*)d_out, nullptr, V_DIM, 256);
}